// Round 11
// baseline (12637.249 us; speedup 1.0000x reference)
//
#include <hip/hip_runtime.h>
#include <hip/hip_bf16.h>
#include <stdint.h>

// ---------------- problem constants ----------------
constexpr int Hh  = 768;     // hidden
constexpr int Ss  = 256;     // seq len
constexpr int Bb  = 32;      // batch
constexpr int G4  = 4 * Hh;  // 3072 gate cols
constexpr int MR  = Bb * Ss; // 8192 rows of the big GEMM
constexpr int NSL = 32;      // slices per layer (24 units each)
constexpr int UPS = 24;      // hidden units per slice
constexpr int LCS = 96;      // gate cols per slice (unit-major: lc = u*4+gi)
constexpr int WP2 = 776;     // padded LDS weight row (1552B stride == 16 mod 128)
constexpr int PB   = 40;     // pool staging row pad
constexpr int NCH  = 3;      // pool n-chunks

typedef short bf16x8 __attribute__((ext_vector_type(8)));
typedef float f32x4  __attribute__((ext_vector_type(4)));
typedef float f32x2  __attribute__((ext_vector_type(2)));
typedef uint32_t u32x4 __attribute__((ext_vector_type(4)));

__device__ __forceinline__ unsigned short f2bf(float f) {
  union { float f; uint32_t u; } v; v.f = f;
  uint32_t u = v.u;
  return (unsigned short)((u + 0x7FFFu + ((u >> 16) & 1u)) >> 16); // RNE
}
__device__ __forceinline__ float bf2f(unsigned short h) {
  union { uint32_t u; float f; } v; v.u = ((uint32_t)h) << 16; return v.f;
}

// ---- asm helpers (XCD-local fast path) ----
__device__ __forceinline__ int xcc_id() {
  int x;
  asm("s_getreg_b32 %0, hwreg(HW_REG_XCC_ID)" : "=s"(x));
  return x & 7;
}
// L1-bypassing load (hits own-XCD L2; sees other-CU plain stores on same XCD)
__device__ __forceinline__ unsigned ld_sc0(const unsigned* p) {
  unsigned v;
  unsigned long long a = (unsigned long long)p;
  asm volatile("global_load_dword %0, %1, off sc0\n\ts_waitcnt vmcnt(0)"
               : "=v"(v) : "v"(a) : "memory");
  return v;
}
// plain (L2-resident) atomic add, no return
__device__ __forceinline__ void atadd_l2(unsigned* p) {
  unsigned one = 1u;
  unsigned long long a = (unsigned long long)p;
  asm volatile("global_atomic_add %0, %1, off" :: "v"(a), "v"(one) : "memory");
}
__device__ __forceinline__ float qsel(float a, float a1, float a2, float a3, int d) {
  float lo = (d & 1) ? a1 : a;
  float hi = (d & 1) ? a3 : a2;
  return (d & 2) ? hi : lo;
}

// ---------------- embedding gather + bf16 cast ----------------
__global__ __launch_bounds__(256) void k_embed(const int* __restrict__ ids,
                                               const float* __restrict__ table,
                                               unsigned short* __restrict__ x_bf) {
  int row = blockIdx.x;                 // b*S+s
  int id  = ids[row];
  const float* src = table + (size_t)id * Hh;
  unsigned short* dst = x_bf + (size_t)row * Hh;
  for (int j = threadIdx.x; j < Hh; j += 256) dst[j] = f2bf(src[j]);
}

// ---------------- fp32 -> bf16 cast ----------------
__global__ __launch_bounds__(256) void k_cast(const float* __restrict__ src,
                                              unsigned short* __restrict__ dst, int n4) {
  int i = blockIdx.x * 256 + threadIdx.x;
  if (i < n4) {
    float4 v = ((const float4*)src)[i];
    uint2 o;
    o.x = (uint32_t)f2bf(v.x) | ((uint32_t)f2bf(v.y) << 16);
    o.y = (uint32_t)f2bf(v.z) | ((uint32_t)f2bf(v.w) << 16);
    ((uint2*)dst)[i] = o;
  }
}

// ---------------- MFMA bf16 TN GEMM -> (s, slice, b, lc) unit-major pre-gates --
__global__ __launch_bounds__(256) void k_gemm_bt(const unsigned short* __restrict__ A,
                                                 const unsigned short* __restrict__ Bw,
                                                 unsigned short* __restrict__ g2,
                                                 const float* __restrict__ bias1,
                                                 const float* __restrict__ bias2,
                                                 int M, int N, int K) {
  constexpr int BM = 128, BN = 128, BK = 64;
  __shared__ unsigned short Asm[BM * BK];
  __shared__ unsigned short Bsm[BN * BK];
  const int tid = threadIdx.x, lane = tid & 63, wave = tid >> 6;
  const int m0 = blockIdx.x * BM, n0 = blockIdx.y * BN;
  const int wm = (wave & 1) * 64, wn = (wave >> 1) * 64;

  f32x4 acc[4][4];
  #pragma unroll
  for (int a = 0; a < 4; ++a)
    #pragma unroll
    for (int b = 0; b < 4; ++b) acc[a][b] = (f32x4){0.f, 0.f, 0.f, 0.f};

  const int nk = K / BK;
  bf16x8 ar[4], br[4];
  #pragma unroll
  for (int r = 0; r < 4; ++r) {
    int fb = r * 4096 + tid * 16;
    int row = fb >> 7;
    int kb  = (fb >> 4) & 7;
    ar[r] = *(const bf16x8*)(A  + (size_t)(m0 + row) * K + kb * 8);
    br[r] = *(const bf16x8*)(Bw + (size_t)(n0 + row) * K + kb * 8);
  }
  for (int it = 0; it < nk; ++it) {
    __syncthreads();
    #pragma unroll
    for (int r = 0; r < 4; ++r) {
      int fb = r * 4096 + tid * 16;
      int row = fb >> 7;
      int kb  = (fb >> 4) & 7;
      int sb  = kb ^ (row & 7);
      *(bf16x8*)((char*)Asm + row * 128 + sb * 16) = ar[r];
      *(bf16x8*)((char*)Bsm + row * 128 + sb * 16) = br[r];
    }
    __syncthreads();
    if (it + 1 < nk) {
      int k0 = (it + 1) * BK;
      #pragma unroll
      for (int r = 0; r < 4; ++r) {
        int fb = r * 4096 + tid * 16;
        int row = fb >> 7;
        int kb  = (fb >> 4) & 7;
        ar[r] = *(const bf16x8*)(A  + (size_t)(m0 + row) * K + k0 + kb * 8);
        br[r] = *(const bf16x8*)(Bw + (size_t)(n0 + row) * K + k0 + kb * 8);
      }
    }
    #pragma unroll
    for (int kk = 0; kk < 2; ++kk) {
      bf16x8 af[4], bfr[4];
      #pragma unroll
      for (int mi = 0; mi < 4; ++mi) {
        int row = wm + mi * 16 + (lane & 15);
        int kb  = kk * 4 + (lane >> 4);
        int sb  = kb ^ (row & 7);
        af[mi] = *(const bf16x8*)((const char*)Asm + row * 128 + sb * 16);
      }
      #pragma unroll
      for (int ni = 0; ni < 4; ++ni) {
        int row = wn + ni * 16 + (lane & 15);
        int kb  = kk * 4 + (lane >> 4);
        int sb  = kb ^ (row & 7);
        bfr[ni] = *(const bf16x8*)((const char*)Bsm + row * 128 + sb * 16);
      }
      #pragma unroll
      for (int mi = 0; mi < 4; ++mi)
        #pragma unroll
        for (int ni = 0; ni < 4; ++ni)
          acc[mi][ni] = __builtin_amdgcn_mfma_f32_16x16x32_bf16(af[mi], bfr[ni], acc[mi][ni], 0, 0, 0);
    }
  }
  #pragma unroll
  for (int mi = 0; mi < 4; ++mi)
    #pragma unroll
    for (int ni = 0; ni < 4; ++ni)
      #pragma unroll
      for (int r = 0; r < 4; ++r) {
        int row = m0 + wm + mi * 16 + (lane >> 4) * 4 + r;   // = b*256 + s
        int n   = n0 + wn + ni * 16 + (lane & 15);           // gate col
        int bb = row >> 8, ss = row & 255;
        int gi = n / Hh, uabs = n - gi * Hh;
        int sl = uabs / UPS, u = uabs - sl * UPS;
        int lc = u * 4 + gi;
        float v = acc[mi][ni][r] + bias1[n] + bias2[n];
        g2[(((size_t)ss * NSL + sl) * Bb + bb) * LCS + lc] = f2bf(v);
      }
}

// ---------------- fused 2-layer LSTM, XCD-local recurrence -------------------
// 256 WGs. Roles by XCD: XCD0 -> L1 (32 slices), XCD1 -> L2-rec, 96 of XCD2..7
// -> L2-input (3-way t-interleave). Validated claim; gid fallback if invalid.
__global__ __launch_bounds__(256) void k_lstm2(
    unsigned short* __restrict__ g2,     // L1 pre-gates; recycled as L2 input partials
    const unsigned short* __restrict__ w_hh0b,
    const unsigned short* __restrict__ w_ih1b,
    const unsigned short* __restrict__ w_hh1b,
    const float* __restrict__ b_ih1,
    const float* __restrict__ b_hh1,
    unsigned short* __restrict__ hseq1,
    unsigned short* __restrict__ hseq1_llc,
    unsigned short* __restrict__ hseq2,
    unsigned short* __restrict__ hseq2_llc,
    unsigned int* __restrict__ sync) {
  __shared__ __align__(16) unsigned short Wlds[96 * WP2];   // 148,992 B
  __shared__ __align__(16) unsigned short hbuf[32][24];     // 1,536 B
  __shared__ int s_role, s_idx, s_fb, lds_step;

  unsigned int* rc      = sync;                 // 16 dwords (claims)
  unsigned int* cnt1loc = sync + 64;
  unsigned int* cnt1ag  = cnt1loc + (size_t)Ss * 256;
  unsigned int* cnt2loc = cnt1ag  + (size_t)Ss * 256;
  unsigned int* cnt2ag  = cnt2loc + (size_t)Ss * 256;
  unsigned int* cntI    = cnt2ag  + (size_t)Ss * 256;       // (t*32+slice)*16

  const int tid = threadIdx.x;
  const int lane = tid & 63, w = tid >> 6;

  if (tid == 0) {
    lds_step = -1;
    int xcd = xcc_id();
    unsigned slot = atomicAdd(&rc[xcd], 1u);
    unsigned gid  = atomicAdd(&rc[8], 1u);
    while (__hip_atomic_load(&rc[8], __ATOMIC_RELAXED, __HIP_MEMORY_SCOPE_AGENT) < 256u)
      __builtin_amdgcn_s_sleep(8);
    unsigned c0 = __hip_atomic_load(&rc[0], __ATOMIC_RELAXED, __HIP_MEMORY_SCOPE_AGENT);
    unsigned c1 = __hip_atomic_load(&rc[1], __ATOMIC_RELAXED, __HIP_MEMORY_SCOPE_AGENT);
    bool valid = (c0 == 32u && c1 == 32u);
    int role, idx = 0, fb = 0;
    if (valid) {
      if (xcd == 0)       { role = 0; idx = (int)slot; }
      else if (xcd == 1)  { role = 1; idx = (int)slot; }
      else {
        unsigned q = atomicAdd(&rc[9], 1u);
        if (q < 96u) { role = 2; idx = (int)q; } else role = 3;
      }
    } else {
      fb = 1;
      if (gid < 32u)      { role = 0; idx = (int)gid; }
      else if (gid < 64u) { role = 1; idx = (int)(gid - 32u); }
      else {
        unsigned q = gid - 64u;
        if (q < 96u) { role = 2; idx = (int)q; } else role = 3;
      }
    }
    s_role = role; s_idx = idx; s_fb = fb;
  }
  __syncthreads();
  const int role = s_role;
  const int idx  = s_idx;
  const int gfb  = s_fb;
  if (role == 3) return;

  const int slice = (role == 2) ? (idx % 32) : idx;
  const int par3  = (role == 2) ? (idx / 32) : 0;
  const int u0 = slice * UPS;

  // ---- stage weight slice (unit-major rows lc = u*4+gi) ----
  {
    const unsigned short* wsrc = (role == 0) ? w_hh0b : (role == 1 ? w_hh1b : w_ih1b);
    for (int cch = tid; cch < 96 * 96; cch += 256) {
      int row = cch / 96, kc = cch - row * 96;
      int u = row >> 2, gi = row & 3;
      *(bf16x8*)&Wlds[row * WP2 + kc * 8] =
          *(const bf16x8*)(wsrc + ((size_t)gi * Hh + u0 + u) * Hh + kc * 8);
    }
  }
  __syncthreads();

  const int bh = w & 1, ch = w >> 1;
  const int l15 = lane & 15, kq = lane >> 4;
  const int C0 = ch * 48;
  const int brow = bh * 16 + l15;
  const int gi_l = l15 & 3;
  const float kk_ = (gi_l == 2) ? 2.f : 1.f;
  const float mm_ = (gi_l == 2) ? 2.f : 1.f;
  const float dd_ = (gi_l == 2) ? -1.f : 0.f;
  const int bkt = slice & 15;
  volatile int* lstep = &lds_step;

  // =========================== L2-input role ================================
  if (role == 2) {
    float bl[3];
    #pragma unroll
    for (int nt = 0; nt < 3; ++nt) {
      int lc = C0 + nt * 16 + l15;
      int u = lc >> 2, gi = lc & 3;
      int gcol = gi * Hh + u0 + u;
      bl[nt] = b_ih1[gcol] + b_hh1[gcol];
    }
    for (int t = par3; t < Ss; t += 3) {
      if (w == 0) {
        const unsigned int* bk = cnt1ag + (size_t)t * 256;
        for (;;) {
          unsigned v = 128;
          if (lane < 16)
            v = __hip_atomic_load(bk + lane * 16, __ATOMIC_RELAXED, __HIP_MEMORY_SCOPE_AGENT);
          if (__all(v >= 8u)) break;
          __builtin_amdgcn_s_sleep(1);
        }
        asm volatile("" ::: "memory");
        if (lane == 0) *lstep = t;
        asm volatile("s_waitcnt lgkmcnt(0)" ::: "memory");
      } else {
        while (*lstep < t) {}
        asm volatile("" ::: "memory");
      }
      const unsigned short* ap = hseq1_llc + ((size_t)t * Bb + brow) * Hh + kq * 8;
      bf16x8 areg[24];
      #pragma unroll
      for (int kk = 0; kk < 24; ++kk) areg[kk] = *(const bf16x8*)(ap + kk * 32);
      f32x4 acc[3][2];
      #pragma unroll
      for (int nt = 0; nt < 3; ++nt) {
        acc[nt][0] = (f32x4){0.f,0.f,0.f,0.f}; acc[nt][1] = (f32x4){0.f,0.f,0.f,0.f};
        const int lc = C0 + nt * 16 + l15;
        #pragma unroll
        for (int kk = 0; kk < 24; ++kk) {
          bf16x8 bfr = *(const bf16x8*)&Wlds[lc * WP2 + kk * 32 + kq * 8];
          acc[nt][kk & 1] = __builtin_amdgcn_mfma_f32_16x16x32_bf16(areg[kk], bfr, acc[nt][kk & 1], 0, 0, 0);
        }
      }
      unsigned short* gout = g2 + (((size_t)t * NSL + slice) * Bb) * LCS;
      #pragma unroll
      for (int nt = 0; nt < 3; ++nt)
        #pragma unroll
        for (int r = 0; r < 4; ++r) {
          float v = acc[nt][0][r] + acc[nt][1][r] + bl[nt];
          __hip_atomic_store(gout + (size_t)(bh * 16 + kq * 4 + r) * LCS + C0 + nt * 16 + l15,
                             f2bf(v), __ATOMIC_RELAXED, __HIP_MEMORY_SCOPE_AGENT);
        }
      asm volatile("s_waitcnt vmcnt(0)" ::: "memory");
      if (lane == 0)
        (void)__hip_atomic_fetch_add(cntI + ((size_t)t * 32 + slice) * 16, 1u,
                                     __ATOMIC_RELAXED, __HIP_MEMORY_SCOPE_AGENT);
    }
    return;
  }

  // =========================== recurrent roles (L1 / L2r) ====================
  const int layer = role;                       // 0 or 1
  unsigned short* hplain = layer ? hseq2 : hseq1;
  unsigned short* hllc   = layer ? hseq2_llc : hseq1_llc;
  const unsigned short* hread = gfb ? hllc : hplain;
  unsigned int* cloc = layer ? cnt2loc : cnt1loc;
  unsigned int* cag  = layer ? cnt2ag  : cnt1ag;

  unsigned short gvC[3][4], gvN[3][4];
  bool okC = false, okN = false;
  unsigned flN = 0;
  float cc[3][4];
  #pragma unroll
  for (int nt = 0; nt < 3; ++nt)
    #pragma unroll
    for (int r = 0; r < 4; ++r) cc[nt][r] = 0.f;

  if (!layer) {
    // L1: pre-gates come straight from gemm output (always valid)
    const unsigned short* grow = g2 + (((size_t)0 * NSL + slice) * Bb) * LCS;
    #pragma unroll
    for (int nt = 0; nt < 3; ++nt)
      #pragma unroll
      for (int r = 0; r < 4; ++r)
        gvC[nt][r] = grow[(size_t)(bh * 16 + kq * 4 + r) * LCS + C0 + nt * 16 + l15];
    okC = true;
  }

  bool wavefb = (gfb != 0);

  for (int t = 0; t < Ss; ++t) {
    // ---- poll own-layer h[t-1] ----
    if (t > 0) {
      if (w == 0) {
        const unsigned int* bl_ = cloc + (size_t)(t - 1) * 256;
        const unsigned int* ba_ = cag  + (size_t)(t - 1) * 256;
        int iters = 0;
        bool ua = wavefb;
        for (;;) {
          unsigned v = 8;
          if (lane < 16)
            v = ua ? __hip_atomic_load(ba_ + lane * 16, __ATOMIC_RELAXED, __HIP_MEMORY_SCOPE_AGENT)
                   : ld_sc0(bl_ + lane * 16);
          if (__all(v >= 8u)) break;
          if (!ua && ++iters > (1 << 15)) { ua = true; wavefb = true; }
          if (ua) __builtin_amdgcn_s_sleep(1);
        }
        asm volatile("" ::: "memory");
        if (lane == 0) *lstep = t;
        asm volatile("s_waitcnt lgkmcnt(0)" ::: "memory");
      } else {
        while (*lstep < t) {}
        asm volatile("" ::: "memory");
      }
    }

    // ---- L2: resolve current-step input partials ----
    if (layer) {
      if (!okC) {
        const unsigned int* fp = cntI + ((size_t)t * 32 + slice) * 16;
        for (;;) {
          unsigned f = __hip_atomic_load(fp, __ATOMIC_RELAXED, __HIP_MEMORY_SCOPE_AGENT);
          if (f >= 4u) break;
          __builtin_amdgcn_s_sleep(1);
        }
        const unsigned short* gp = g2 + (((size_t)t * NSL + slice) * Bb) * LCS;
        #pragma unroll
        for (int nt = 0; nt < 3; ++nt)
          #pragma unroll
          for (int r = 0; r < 4; ++r)
            gvC[nt][r] = __hip_atomic_load(
                gp + (size_t)(bh * 16 + kq * 4 + r) * LCS + C0 + nt * 16 + l15,
                __ATOMIC_RELAXED, __HIP_MEMORY_SCOPE_AGENT);
      }
      // speculative issue for t+1 (validated by flag loaded at t-1 tail)
      okN = false;
      if (t + 1 < Ss && flN >= 4u) {
        const unsigned short* gp = g2 + (((size_t)(t + 1) * NSL + slice) * Bb) * LCS;
        #pragma unroll
        for (int nt = 0; nt < 3; ++nt)
          #pragma unroll
          for (int r = 0; r < 4; ++r)
            gvN[nt][r] = __hip_atomic_load(
                gp + (size_t)(bh * 16 + kq * 4 + r) * LCS + C0 + nt * 16 + l15,
                __ATOMIC_RELAXED, __HIP_MEMORY_SCOPE_AGENT);
        okN = true;
      }
    }

    // ---- recurrent GEMM ----
    f32x4 acc[3][2];
    #pragma unroll
    for (int nt = 0; nt < 3; ++nt) {
      acc[nt][0] = (f32x4){0.f,0.f,0.f,0.f}; acc[nt][1] = (f32x4){0.f,0.f,0.f,0.f};
    }
    if (t > 0) {
      const unsigned short* ap = hread + ((size_t)(t - 1) * Bb + brow) * Hh + kq * 8;
      bf16x8 areg[24];
      #pragma unroll
      for (int kk = 0; kk < 24; ++kk) areg[kk] = *(const bf16x8*)(ap + kk * 32);
      #pragma unroll
      for (int nt = 0; nt < 3; ++nt) {
        const int lc = C0 + nt * 16 + l15;
        #pragma unroll
        for (int kk = 0; kk < 24; ++kk) {
          bf16x8 bfr = *(const bf16x8*)&Wlds[lc * WP2 + kk * 32 + kq * 8];
          acc[nt][kk & 1] = __builtin_amdgcn_mfma_f32_16x16x32_bf16(areg[kk], bfr, acc[nt][kk & 1], 0, 0, 0);
        }
      }
    }

    // ---- activations + quad-exchange pointwise ----
    #pragma unroll
    for (int nt = 0; nt < 3; ++nt)
      #pragma unroll
      for (int r = 0; r < 4; ++r) {
        float v = acc[nt][0][r] + acc[nt][1][r] + bf2f(gvC[nt][r]);
        float a = mm_ / (1.f + __expf(-kk_ * v)) + dd_;
        float a1 = __shfl_xor(a, 1);
        float a2 = __shfl_xor(a, 2);
        float a3 = __shfl_xor(a1, 2);
        float i_ = qsel(a, a1, a2, a3, gi_l);
        float f_ = qsel(a, a1, a2, a3, gi_l ^ 1);
        float g_ = qsel(a, a1, a2, a3, gi_l ^ 2);
        float o_ = qsel(a, a1, a2, a3, gi_l ^ 3);
        float cn = f_ * cc[nt][r] + i_ * g_;
        cc[nt][r] = cn;
        float e = __expf(-2.f * cn);
        float hv = o_ * (1.f - e) / (1.f + e);
        if (gi_l == 0)
          hbuf[bh * 16 + kq * 4 + r][(C0 + nt * 16 + l15) >> 2] = f2bf(hv);
      }

    // ---- issue next-step input loads (L1: plain from gemm; vmcnt below covers) ----
    if (!layer && t + 1 < Ss) {
      const unsigned short* grow = g2 + (((size_t)(t + 1) * NSL + slice) * Bb) * LCS;
      #pragma unroll
      for (int nt = 0; nt < 3; ++nt)
        #pragma unroll
        for (int r = 0; r < 4; ++r)
          gvN[nt][r] = grow[(size_t)(bh * 16 + kq * 4 + r) * LCS + C0 + nt * 16 + l15];
      okN = true;
    }

    asm volatile("s_waitcnt lgkmcnt(0)" ::: "memory");  // hbuf writes visible (own wave)

    // ---- publish h (this wave's 16 rows x 12-unit half) ----
    if (lane < 48) {
      int b = lane / 3, j = lane - (lane / 3) * 3;
      unsigned long long x = *(const unsigned long long*)&hbuf[bh * 16 + b][ch * 12 + j * 4];
      size_t off8 = ((size_t)t * Bb + bh * 16 + b) * Hh + u0 + ch * 12 + j * 4;
      *(unsigned long long*)(hplain + off8) = x;   // plain: own-XCD L2
      __hip_atomic_store((unsigned long long*)(hllc + off8), x,
                         __ATOMIC_RELAXED, __HIP_MEMORY_SCOPE_AGENT);
    }
    asm volatile("s_waitcnt vmcnt(0)" ::: "memory");  // both stores + input loads acked
    if (lane == 0) atadd_l2(cloc + (size_t)t * 256 + bkt * 16);
    if (lane == 1)
      (void)__hip_atomic_fetch_add(cag + (size_t)t * 256 + bkt * 16, 1u,
                                   __ATOMIC_RELAXED, __HIP_MEMORY_SCOPE_AGENT);

    // ---- L2 tail: load flag for t+2 (value used at t+1 start) ----
    if (layer && t + 2 < Ss)
      flN = __hip_atomic_load(cntI + ((size_t)(t + 2) * 32 + slice) * 16,
                              __ATOMIC_RELAXED, __HIP_MEMORY_SCOPE_AGENT);

    // shift input regs
    #pragma unroll
    for (int nt = 0; nt < 3; ++nt)
      #pragma unroll
      for (int r = 0; r < 4; ++r) gvC[nt][r] = gvN[nt][r];
    okC = okN;
  }
}

// ---------------- pool partial, n-split: grid (Ss, NCH) ----------------------
__global__ __launch_bounds__(256) void k_pool_partial(const unsigned short* __restrict__ hseq2,
                                                      const float* __restrict__ pw,
                                                      float* __restrict__ partial) {
  __shared__ __align__(16) unsigned short osm[Hh * PB];
  const int tid = threadIdx.x;
  const int s = blockIdx.x, nc = blockIdx.y;
  for (int b = 0; b < Bb; ++b) {
    const unsigned short* src = hseq2 + ((size_t)s * Bb + b) * Hh;
    for (int k = tid; k < Hh; k += 256) osm[k * PB + b] = src[k];
  }
  __syncthreads();
  f32x2 acc[16];
  #pragma unroll
  for (int bp = 0; bp < 16; ++bp) acc[bp] = (f32x2){0.f, 0.f};
  const float* pbase = pw + (size_t)s * Hh * Hh + nc * 256 + tid;
  #pragma unroll 4
  for (int k = 0; k < Hh; ++k) {
    float wv = pbase[(size_t)k * Hh];
    u32x4 h0 = *(const u32x4*)&osm[k * PB + 0];
    u32x4 h1 = *(const u32x4*)&osm[k * PB + 8];
    u32x4 h2 = *(const u32x4*)&osm[k * PB + 16];
    u32x4 h3 = *(const u32x4*)&osm[k * PB + 24];
    uint32_t hw[16] = {h0[0],h0[1],h0[2],h0[3], h1[0],h1[1],h1[2],h1[3],
                       h2[0],h2[1],h2[2],h2[3], h3[0],h3[1],h3[2],h3[3]};
    #pragma unroll
    for (int bp = 0; bp < 16; ++bp) {
      uint32_t pv = hw[bp];
      f32x2 ov;
      ov.x = __uint_as_float(pv << 16);
      ov.y = __uint_as_float(pv & 0xffff0000u);
      acc[bp] += ov * wv;
    }
  }
  float* pout = partial + (size_t)(s * NCH + nc) * (Bb * 256);
  #pragma unroll
  for (int bp = 0; bp < 16; ++bp) {
    pout[(size_t)(bp * 2 + 0) * 256 + tid] = acc[bp].x;
    pout[(size_t)(bp * 2 + 1) * 256 + tid] = acc[bp].y;
  }
}

__global__ __launch_bounds__(256) void k_pool_reduce(const float* __restrict__ partial,
                                                     const float* __restrict__ pool_b,
                                                     float* __restrict__ seq_out) {
  int i = blockIdx.x * 256 + threadIdx.x;   // b*768+n
  int b = i / Hh, n = i - b * Hh;
  int nchunk = n >> 8, nn = n & 255;
  float acc = pool_b[n];
  const float* p = partial + (size_t)nchunk * (Bb * 256) + b * 256 + nn;
  #pragma unroll 8
  for (int t = 0; t < Ss; ++t) acc += p[(size_t)t * NCH * (Bb * 256)];
  seq_out[i] = acc;
}

// ---------------- entity masked max + logits ----------------
__global__ __launch_bounds__(256) void k_entity_logits(const unsigned short* __restrict__ hseq2,
                                                       const float* __restrict__ seq_out,
                                                       const int* __restrict__ entity_ids,
                                                       const float* __restrict__ lin_w,
                                                       const float* __restrict__ lin_b,
                                                       float* __restrict__ logits_ws,
                                                       float* __restrict__ dlogits) {
  const int b = blockIdx.x, tid = threadIdx.x;
  float m0 = -1e30f, m1 = -1e30f, m2 = -1e30f;
  for (int s = 0; s < Ss; ++s) {
    bool e = entity_ids[b * Ss + s] == 1;
    const unsigned short* row = hseq2 + ((size_t)s * Bb + b) * Hh;
    float v0 = bf2f(row[tid]);
    float v1 = bf2f(row[256 + tid]);
    float v2 = bf2f(row[512 + tid]);
    v0 = e ? v0 : 0.f; v1 = e ? v1 : 0.f; v2 = e ? v2 : 0.f;
    m0 = fmaxf(m0, v0); m1 = fmaxf(m1, v1); m2 = fmaxf(m2, v2);
  }
  __shared__ float red[512];
  float p0 = 0.f, p1 = 0.f;
  float mm[3] = {m0, m1, m2};
  #pragma unroll
  for (int j = 0; j < 3; ++j) {
    int n = j * 256 + tid;
    float bo = fmaxf(mm[j], seq_out[b * Hh + n]);
    p0 += bo * lin_w[n * 2 + 0];
    p1 += bo * lin_w[n * 2 + 1];
  }
  red[tid] = p0; red[256 + tid] = p1;
  __syncthreads();
  for (int off = 128; off > 0; off >>= 1) {
    if (tid < off) { red[tid] += red[tid + off]; red[256 + tid] += red[256 + tid + off]; }
    __syncthreads();
  }
  if (tid == 0) {
    float l0 = red[0] + lin_b[0], l1 = red[256] + lin_b[1];
    logits_ws[b * 2] = l0; logits_ws[b * 2 + 1] = l1;
    dlogits[b * 2] = l0;  dlogits[b * 2 + 1] = l1;
  }
}

// ---------------- BCEWithLogits mean loss ----------------
__global__ void k_loss(const float* __restrict__ logits, const int* __restrict__ lab,
                       float* __restrict__ dout) {
  __shared__ float red[64];
  int i = threadIdx.x;
  float l = logits[i];
  float y = (float)lab[i];
  red[i] = fmaxf(l, 0.f) - l * y + log1pf(__expf(-fabsf(l)));
  __syncthreads();
  for (int off = 32; off > 0; off >>= 1) {
    if (i < off) red[i] += red[i + off];
    __syncthreads();
  }
  if (i == 0) dout[0] = red[0] * (1.f / 64.f);
}

// ---------------- launcher ----------------
extern "C" void kernel_launch(void* const* d_in, const int* in_sizes, int n_in,
                              void* d_out, int out_size, void* d_ws, size_t ws_size,
                              hipStream_t stream) {
  const int*   input_ids  = (const int*)d_in[0];
  const int*   seq_label  = (const int*)d_in[3];
  const int*   entity_ids = (const int*)d_in[4];
  const float* embed      = (const float*)d_in[5];
  const float* w_ih0      = (const float*)d_in[6];
  const float* w_hh0      = (const float*)d_in[7];
  const float* b_ih0      = (const float*)d_in[8];
  const float* b_hh0      = (const float*)d_in[9];
  const float* w_ih1      = (const float*)d_in[10];
  const float* w_hh1      = (const float*)d_in[11];
  const float* b_ih1      = (const float*)d_in[12];
  const float* b_hh1      = (const float*)d_in[13];
  const float* pool_w     = (const float*)d_in[14];
  const float* pool_b     = (const float*)d_in[15];
  const float* lin_w      = (const float*)d_in[16];
  const float* lin_b      = (const float*)d_in[17];
  float* out = (float*)d_out;

  const size_t SZ_XO = (size_t)Bb * Ss * Hh * 2;   // 12.58 MB
  const size_t SZ_W  = (size_t)G4 * Hh * 2;        //  4.72 MB
  const size_t SZ_G  = (size_t)Bb * Ss * G4 * 2;   // 50.33 MB
  const size_t SZ_SY = (size_t)(64 + 4 * Ss * 256 + Ss * 32 * 16) * 4;  // ~1.54 MB
  char* ws = (char*)d_ws;
  size_t off = 0;
  unsigned short* x_bf   = (unsigned short*)(ws + off); off += SZ_XO;
  unsigned short* wb_ih0 = (unsigned short*)(ws + off); off += SZ_W;
  unsigned short* wb_hh0 = (unsigned short*)(ws + off); off += SZ_W;
  unsigned short* wb_ih1 = (unsigned short*)(ws + off); off += SZ_W;
  unsigned short* wb_hh1 = (unsigned short*)(ws + off); off += SZ_W;
  unsigned short* g2     = (unsigned short*)(ws + off); off += SZ_G;   // also L2-input partials
  unsigned short* hseq1  = (unsigned short*)(ws + off); off += SZ_XO;
  unsigned short* h1llc  = (unsigned short*)(ws + off); off += SZ_XO;
  unsigned short* hseq2  = (unsigned short*)(ws + off); off += SZ_XO;
  unsigned short* h2llc  = (unsigned short*)(ws + off); off += SZ_XO;
  float*          seq_out= (float*)(ws + off);          off += (size_t)Bb * Hh * 4;
  float*          logits = (float*)(ws + off);          off += 1024;
  unsigned int*   syncb  = (unsigned int*)(ws + off);   off += SZ_SY;
  float*          partial = (float*)ws;  // aliases dead x_bf..wb region after k_lstm2

  hipMemsetAsync(syncb, 0, SZ_SY, stream);

  k_embed<<<Bb * Ss, 256, 0, stream>>>(input_ids, embed, x_bf);
  int n4 = (G4 * Hh) / 4;
  int cgrid = (n4 + 255) / 256;
  k_cast<<<cgrid, 256, 0, stream>>>(w_ih0, wb_ih0, n4);
  k_cast<<<cgrid, 256, 0, stream>>>(w_hh0, wb_hh0, n4);
  k_cast<<<cgrid, 256, 0, stream>>>(w_ih1, wb_ih1, n4);
  k_cast<<<cgrid, 256, 0, stream>>>(w_hh1, wb_hh1, n4);

  dim3 ggrid(MR / 128, G4 / 128);
  k_gemm_bt<<<ggrid, 256, 0, stream>>>(x_bf, wb_ih0, g2, b_ih0, b_hh0, MR, G4, Hh);

  k_lstm2<<<256, 256, 0, stream>>>(g2, wb_hh0, wb_ih1, wb_hh1,
                                   b_ih1, b_hh1, hseq1, h1llc, hseq2, h2llc, syncb);

  dim3 pgrid(Ss, NCH);
  k_pool_partial<<<pgrid, 256, 0, stream>>>(hseq2, pool_w, partial);
  k_pool_reduce<<<(Bb * Hh) / 256, 256, 0, stream>>>(partial, pool_b, seq_out);
  k_entity_logits<<<Bb, 256, 0, stream>>>(hseq2, seq_out, entity_ids, lin_w, lin_b,
                                          logits, out + 1);
  k_loss<<<1, 64, 0, stream>>>(logits, seq_label, out);
}

// Round 12
// 2188.680 us; speedup vs baseline: 5.7739x; 5.7739x over previous
//
#include <hip/hip_runtime.h>
#include <hip/hip_bf16.h>
#include <stdint.h>

// ---------------- problem constants ----------------
constexpr int Hh  = 768;     // hidden
constexpr int Ss  = 256;     // seq len
constexpr int Bb  = 32;      // batch
constexpr int NWGL = 96;     // LSTM workgroups per layer
constexpr int UPW8 = Hh / NWGL;  // 8 hidden units per WG
constexpr int LCW  = 4 * UPW8;   // 32 gate cols per WG
constexpr int WPAD = Hh + 8;     // padded weight row: stride 1552B == 16B mod 128B
constexpr int CPT  = 256;        // counter dwords per step (16 buckets x 16-dword stride)
constexpr int PB   = 40;         // pool staging row pad
constexpr int NCH  = 3;          // pool n-chunks

typedef short bf16x8 __attribute__((ext_vector_type(8)));
typedef float f32x4  __attribute__((ext_vector_type(4)));
typedef float f32x2  __attribute__((ext_vector_type(2)));
typedef uint32_t u32x4 __attribute__((ext_vector_type(4)));

__device__ __forceinline__ unsigned short f2bf(float f) {
  union { float f; uint32_t u; } v; v.f = f;
  uint32_t u = v.u;
  return (unsigned short)((u + 0x7FFFu + ((u >> 16) & 1u)) >> 16); // RNE
}
__device__ __forceinline__ float bf2f(unsigned short h) {
  union { uint32_t u; float f; } v; v.u = ((uint32_t)h) << 16; return v.f;
}

// ---------------- embedding gather + bf16 cast -> (s, b, H) layout ----------
__global__ __launch_bounds__(256) void k_embed(const int* __restrict__ ids,
                                               const float* __restrict__ table,
                                               unsigned short* __restrict__ x_bf) {
  int row = blockIdx.x;                 // b*S+s
  int b = row / Ss, s = row - b * Ss;
  int id  = ids[row];
  const float* src = table + (size_t)id * Hh;
  unsigned short* dst = x_bf + ((size_t)s * Bb + b) * Hh;
  for (int j = threadIdx.x; j < Hh; j += 256) dst[j] = f2bf(src[j]);
}

// ---------------- fused 2-layer LSTM, producer/consumer waves ----------------
// WGs 0..95: layer-1; 96..191: layer-2. Per-WG: waves 0,1 = recurrence
// (Whh GEMM + pointwise + publish), waves 2,3 = input-GEMM producers
// (L1: x@Wih0 -- no polling; L2: h1@Wih1 -- polls cnt1). Weights staged
// fp32->bf16 inline. Counters: 16 buckets x 16-dword stride, threshold 12.
__global__ __launch_bounds__(256) void k_lstm2(
    const unsigned short* __restrict__ x_bf,
    const float* __restrict__ w_ih0, const float* __restrict__ w_hh0,
    const float* __restrict__ w_ih1, const float* __restrict__ w_hh1,
    const float* __restrict__ b_ih0, const float* __restrict__ b_hh0,
    const float* __restrict__ b_ih1, const float* __restrict__ b_hh1,
    unsigned short* __restrict__ hseq1,
    unsigned short* __restrict__ hseq2,
    unsigned int* __restrict__ sync) {
  __shared__ __align__(16) unsigned short Whh[LCW * WPAD];   // 48.5 KB
  __shared__ __align__(16) unsigned short Wih[LCW * WPAD];   // 48.5 KB
  __shared__ __align__(16) unsigned short hbuf[2][16][8];
  __shared__ __align__(16) float gsum[2][2][16][33];         // [slot][bh][row][col]
  __shared__ int prodf[2], consf[2];
  __shared__ int stepC, stepP;

  const int wgid = blockIdx.x;
  const int tid = threadIdx.x;
  const int lane = tid & 63, w = tid >> 6;     // w in {0..3}
  unsigned int* cnt1 = sync;
  unsigned int* cnt2 = sync + Ss * CPT;

  const int layer = wgid >= NWGL;
  const int wg = layer ? wgid - NWGL : wgid;
  const int u0 = wg * UPW8;
  const int bkt = wg & 15;

  if (tid < 2) { prodf[tid] = 0; consf[tid] = -1; }
  if (tid == 2) stepC = 0;
  if (tid == 3) stepP = 0;

  // ---- stage weight slices fp32 -> bf16 into padded LDS rows (all 4 waves) --
  {
    const float* whsrc = layer ? w_hh1 : w_hh0;
    const float* wisrc = layer ? w_ih1 : w_ih0;
    for (int cch = tid; cch < LCW * 96; cch += 256) {
      int row = cch / 96, kc = cch - row * 96;
      int gi = row >> 3, u = row & 7;
      const float* sp = whsrc + ((size_t)gi * Hh + u0 + u) * Hh + kc * 8;
      float4 va = ((const float4*)sp)[0], vb = ((const float4*)sp)[1];
      bf16x8 pk;
      pk[0] = (short)f2bf(va.x); pk[1] = (short)f2bf(va.y);
      pk[2] = (short)f2bf(va.z); pk[3] = (short)f2bf(va.w);
      pk[4] = (short)f2bf(vb.x); pk[5] = (short)f2bf(vb.y);
      pk[6] = (short)f2bf(vb.z); pk[7] = (short)f2bf(vb.w);
      *(bf16x8*)&Whh[row * WPAD + kc * 8] = pk;
      const float* sp2 = wisrc + ((size_t)gi * Hh + u0 + u) * Hh + kc * 8;
      float4 vc = ((const float4*)sp2)[0], vd = ((const float4*)sp2)[1];
      bf16x8 pk2;
      pk2[0] = (short)f2bf(vc.x); pk2[1] = (short)f2bf(vc.y);
      pk2[2] = (short)f2bf(vc.z); pk2[3] = (short)f2bf(vc.w);
      pk2[4] = (short)f2bf(vd.x); pk2[5] = (short)f2bf(vd.y);
      pk2[6] = (short)f2bf(vd.z); pk2[7] = (short)f2bf(vd.w);
      *(bf16x8*)&Wih[row * WPAD + kc * 8] = pk2;
    }
  }
  __syncthreads();   // the ONLY workgroup barrier

  const int l15 = lane & 15, kq = lane >> 4;
  const bool lo8 = (l15 < 8);
  volatile int* scp = &stepC;
  volatile int* spp = &stepP;

  // ======================= producer waves (w = 2,3) ==========================
  if (w >= 2) {
    const int bh = w - 2;
    const int brow = bh * 16 + l15;
    for (int t = 0; t < Ss; ++t) {
      if (layer) {
        // need h1[t] from all 96 L1 WGs; only w2 polls, w3 rides LDS step
        if (w == 2) {
          const unsigned int* bk = cnt1 + (size_t)t * CPT;
          for (;;) {
            unsigned v = 12;
            if (lane < 16)
              v = __hip_atomic_load(bk + lane * 16, __ATOMIC_RELAXED, __HIP_MEMORY_SCOPE_AGENT);
            if (__all(v >= 12u)) break;
            __builtin_amdgcn_s_sleep(2);
          }
          asm volatile("" ::: "memory");
          if (lane == 0) *spp = t + 1;
          asm volatile("s_waitcnt lgkmcnt(0)" ::: "memory");
        } else {
          while (*spp < t + 1) __builtin_amdgcn_s_sleep(1);
          asm volatile("" ::: "memory");
        }
      }
      const unsigned short* ap = (layer ? hseq1 : x_bf)
                               + ((size_t)t * Bb + brow) * Hh + kq * 8;
      bf16x8 areg[24];
      #pragma unroll
      for (int kk = 0; kk < 24; ++kk) areg[kk] = *(const bf16x8*)(ap + kk * 32);
      f32x4 aI[2][2];
      #pragma unroll
      for (int nt = 0; nt < 2; ++nt) {
        aI[nt][0] = (f32x4){0.f,0.f,0.f,0.f}; aI[nt][1] = (f32x4){0.f,0.f,0.f,0.f};
        const int c = nt * 16 + l15;
        #pragma unroll
        for (int kk = 0; kk < 24; ++kk) {
          bf16x8 bfr = *(const bf16x8*)&Wih[c * WPAD + kk * 32 + kq * 8];
          aI[nt][kk & 1] = __builtin_amdgcn_mfma_f32_16x16x32_bf16(areg[kk], bfr, aI[nt][kk & 1], 0, 0, 0);
        }
      }
      // wait for free ring slot (consumer must have consumed t-2)
      while (__hip_atomic_load(&consf[bh], __ATOMIC_RELAXED, __HIP_MEMORY_SCOPE_WORKGROUP) < t - 1)
        __builtin_amdgcn_s_sleep(0);
      const int par = t & 1;
      #pragma unroll
      for (int nt = 0; nt < 2; ++nt)
        #pragma unroll
        for (int r = 0; r < 4; ++r)
          gsum[par][bh][kq * 4 + r][nt * 16 + l15] = aI[nt][0][r] + aI[nt][1][r];
      __hip_atomic_store(&prodf[bh], t + 1, __ATOMIC_RELEASE, __HIP_MEMORY_SCOPE_WORKGROUP);
    }
    return;
  }

  // ======================= consumer waves (w = 0,1) ==========================
  const int bh = w;
  const int brow = bh * 16 + l15;
  const float k1 = lo8 ? 2.f : 1.f;            // nt1 lanes: g (tanh) if lo8 else o
  const float m1 = lo8 ? 2.f : 1.f;
  const float d1 = lo8 ? -1.f : 0.f;

  float bl[2];
  #pragma unroll
  for (int nt = 0; nt < 2; ++nt) {
    int c = nt * 16 + l15;
    int gcol = (c >> 3) * Hh + u0 + (c & 7);
    bl[nt] = layer ? (b_ih1[gcol] + b_hh1[gcol]) : (b_ih0[gcol] + b_hh0[gcol]);
  }

  float cc[4] = {0.f, 0.f, 0.f, 0.f};
  unsigned short* hout = layer ? hseq2 : hseq1;
  unsigned int* mycnt = layer ? cnt2 : cnt1;

  for (int t = 0; t < Ss; ++t) {
    f32x4 aW[2][2];
    #pragma unroll
    for (int nt = 0; nt < 2; ++nt) {
      aW[nt][0] = (f32x4){0.f,0.f,0.f,0.f}; aW[nt][1] = (f32x4){0.f,0.f,0.f,0.f};
    }
    if (t > 0) {
      // own-layer h[t-1]; only w0 polls, w1 rides LDS step
      if (w == 0) {
        const unsigned int* bown = mycnt + (size_t)(t - 1) * CPT;
        for (;;) {
          unsigned v = 12;
          if (lane < 16)
            v = __hip_atomic_load(bown + lane * 16, __ATOMIC_RELAXED, __HIP_MEMORY_SCOPE_AGENT);
          if (__all(v >= 12u)) break;
          __builtin_amdgcn_s_sleep(2);
        }
        asm volatile("" ::: "memory");
        if (lane == 0) *scp = t;
        asm volatile("s_waitcnt lgkmcnt(0)" ::: "memory");
      } else {
        while (*scp < t) __builtin_amdgcn_s_sleep(1);
        asm volatile("" ::: "memory");
      }
      const unsigned short* ap = hout + ((size_t)(t - 1) * Bb + brow) * Hh + kq * 8;
      bf16x8 areg[24];
      #pragma unroll
      for (int kk = 0; kk < 24; ++kk) areg[kk] = *(const bf16x8*)(ap + kk * 32);
      #pragma unroll
      for (int nt = 0; nt < 2; ++nt) {
        const int c = nt * 16 + l15;
        #pragma unroll
        for (int kk = 0; kk < 24; ++kk) {
          bf16x8 bfr = *(const bf16x8*)&Whh[c * WPAD + kk * 32 + kq * 8];
          aW[nt][kk & 1] = __builtin_amdgcn_mfma_f32_16x16x32_bf16(areg[kk], bfr, aW[nt][kk & 1], 0, 0, 0);
        }
      }
    }

    // ---- input-path term from producer ring (both layers) ----
    float gin[2][4];
    {
      while (__hip_atomic_load(&prodf[bh], __ATOMIC_ACQUIRE, __HIP_MEMORY_SCOPE_WORKGROUP) < t + 1)
        __builtin_amdgcn_s_sleep(0);
      const int par = t & 1;
      #pragma unroll
      for (int nt = 0; nt < 2; ++nt)
        #pragma unroll
        for (int r = 0; r < 4; ++r)
          gin[nt][r] = gsum[par][bh][kq * 4 + r][nt * 16 + l15] + bl[nt];
      __hip_atomic_store(&consf[bh], t, __ATOMIC_RELEASE, __HIP_MEMORY_SCOPE_WORKGROUP);
    }

    // ---- activations ----
    float act0[4], act1[4];
    #pragma unroll
    for (int r = 0; r < 4; ++r) {
      float v0 = aW[0][0][r] + aW[0][1][r] + gin[0][r];
      act0[r] = 1.f / (1.f + __expf(-v0));                   // i or f: sigmoid
      float v1 = aW[1][0][r] + aW[1][1][r] + gin[1][r];
      act1[r] = m1 / (1.f + __expf(-k1 * v1)) + d1;          // g: tanh, o: sigmoid
    }

    // ---- pointwise c/h via lane^8 shuffle ----
    #pragma unroll
    for (int r = 0; r < 4; ++r) {
      float p0 = __shfl_xor(act0[r], 8);
      float p1 = __shfl_xor(act1[r], 8);
      float iv = lo8 ? act0[r] : p0;
      float fv = lo8 ? p0 : act0[r];
      float gv = lo8 ? act1[r] : p1;
      float ov = lo8 ? p1 : act1[r];
      float cn = fv * cc[r] + iv * gv;
      cc[r] = cn;
      float e = __expf(-2.f * cn);
      float hv = ov * (1.f - e) / (1.f + e);
      if (lo8) hbuf[w][kq * 4 + r][l15] = f2bf(hv);
    }
    asm volatile("s_waitcnt lgkmcnt(0)" ::: "memory");   // wave's hbuf writes done

    // ---- publish h (16 lanes x 16B); vmcnt; per-wave bucket add ----
    if (lane < 16) {
      const unsigned long long* hb = (const unsigned long long*)&hbuf[w][lane][0];
      unsigned long long x0 = hb[0], x1 = hb[1];
      unsigned long long* hp =
          (unsigned long long*)(hout + ((size_t)t * Bb + (bh * 16 + lane)) * Hh + u0);
      __hip_atomic_store(hp + 0, x0, __ATOMIC_RELAXED, __HIP_MEMORY_SCOPE_AGENT);
      __hip_atomic_store(hp + 1, x1, __ATOMIC_RELAXED, __HIP_MEMORY_SCOPE_AGENT);
    }
    asm volatile("s_waitcnt vmcnt(0)" ::: "memory");     // h acked at LLC
    if (lane == 0) {
      unsigned int* cp = mycnt + (size_t)t * CPT + bkt * 16;
      (void)__hip_atomic_fetch_add(cp, 1u, __ATOMIC_RELAXED, __HIP_MEMORY_SCOPE_AGENT);
    }
  }
}

// ---------------- pool partial, n-split: grid (Ss, NCH) ----------------------
__global__ __launch_bounds__(256) void k_pool_partial(const unsigned short* __restrict__ hseq2,
                                                      const float* __restrict__ pw,
                                                      float* __restrict__ partial) {
  __shared__ __align__(16) unsigned short osm[Hh * PB];
  const int tid = threadIdx.x;
  const int s = blockIdx.x, nc = blockIdx.y;
  for (int b = 0; b < Bb; ++b) {
    const unsigned short* src = hseq2 + ((size_t)s * Bb + b) * Hh;
    for (int k = tid; k < Hh; k += 256) osm[k * PB + b] = src[k];
  }
  __syncthreads();
  f32x2 acc[16];
  #pragma unroll
  for (int bp = 0; bp < 16; ++bp) acc[bp] = (f32x2){0.f, 0.f};
  const float* pbase = pw + (size_t)s * Hh * Hh + nc * 256 + tid;
  #pragma unroll 4
  for (int k = 0; k < Hh; ++k) {
    float wv = pbase[(size_t)k * Hh];
    u32x4 h0 = *(const u32x4*)&osm[k * PB + 0];
    u32x4 h1 = *(const u32x4*)&osm[k * PB + 8];
    u32x4 h2 = *(const u32x4*)&osm[k * PB + 16];
    u32x4 h3 = *(const u32x4*)&osm[k * PB + 24];
    uint32_t hw[16] = {h0[0],h0[1],h0[2],h0[3], h1[0],h1[1],h1[2],h1[3],
                       h2[0],h2[1],h2[2],h2[3], h3[0],h3[1],h3[2],h3[3]};
    #pragma unroll
    for (int bp = 0; bp < 16; ++bp) {
      uint32_t pv = hw[bp];
      f32x2 ov;
      ov.x = __uint_as_float(pv << 16);
      ov.y = __uint_as_float(pv & 0xffff0000u);
      acc[bp] += ov * wv;
    }
  }
  float* pout = partial + (size_t)(s * NCH + nc) * (Bb * 256);
  #pragma unroll
  for (int bp = 0; bp < 16; ++bp) {
    pout[(size_t)(bp * 2 + 0) * 256 + tid] = acc[bp].x;
    pout[(size_t)(bp * 2 + 1) * 256 + tid] = acc[bp].y;
  }
}

__global__ __launch_bounds__(256) void k_pool_reduce(const float* __restrict__ partial,
                                                     const float* __restrict__ pool_b,
                                                     float* __restrict__ seq_out) {
  int i = blockIdx.x * 256 + threadIdx.x;   // b*768+n
  int b = i / Hh, n = i - b * Hh;
  int nchunk = n >> 8, nn = n & 255;
  float acc = pool_b[n];
  const float* p = partial + (size_t)nchunk * (Bb * 256) + b * 256 + nn;
  #pragma unroll 8
  for (int t = 0; t < Ss; ++t) acc += p[(size_t)t * NCH * (Bb * 256)];
  seq_out[i] = acc;
}

// ---------------- entity masked max + logits ----------------
__global__ __launch_bounds__(256) void k_entity_logits(const unsigned short* __restrict__ hseq2,
                                                       const float* __restrict__ seq_out,
                                                       const int* __restrict__ entity_ids,
                                                       const float* __restrict__ lin_w,
                                                       const float* __restrict__ lin_b,
                                                       float* __restrict__ logits_ws,
                                                       float* __restrict__ dlogits) {
  const int b = blockIdx.x, tid = threadIdx.x;
  float m0 = -1e30f, m1 = -1e30f, m2 = -1e30f;
  for (int s = 0; s < Ss; ++s) {
    bool e = entity_ids[b * Ss + s] == 1;
    const unsigned short* row = hseq2 + ((size_t)s * Bb + b) * Hh;
    float v0 = bf2f(row[tid]);
    float v1 = bf2f(row[256 + tid]);
    float v2 = bf2f(row[512 + tid]);
    v0 = e ? v0 : 0.f; v1 = e ? v1 : 0.f; v2 = e ? v2 : 0.f;
    m0 = fmaxf(m0, v0); m1 = fmaxf(m1, v1); m2 = fmaxf(m2, v2);
  }
  __shared__ float red[512];
  float p0 = 0.f, p1 = 0.f;
  float mm[3] = {m0, m1, m2};
  #pragma unroll
  for (int j = 0; j < 3; ++j) {
    int n = j * 256 + tid;
    float bo = fmaxf(mm[j], seq_out[b * Hh + n]);
    p0 += bo * lin_w[n * 2 + 0];
    p1 += bo * lin_w[n * 2 + 1];
  }
  red[tid] = p0; red[256 + tid] = p1;
  __syncthreads();
  for (int off = 128; off > 0; off >>= 1) {
    if (tid < off) { red[tid] += red[tid + off]; red[256 + tid] += red[256 + tid + off]; }
    __syncthreads();
  }
  if (tid == 0) {
    float l0 = red[0] + lin_b[0], l1 = red[256] + lin_b[1];
    logits_ws[b * 2] = l0; logits_ws[b * 2 + 1] = l1;
    dlogits[b * 2] = l0;  dlogits[b * 2 + 1] = l1;
  }
}

// ---------------- BCEWithLogits mean loss ----------------
__global__ void k_loss(const float* __restrict__ logits, const int* __restrict__ lab,
                       float* __restrict__ dout) {
  __shared__ float red[64];
  int i = threadIdx.x;
  float l = logits[i];
  float y = (float)lab[i];
  red[i] = fmaxf(l, 0.f) - l * y + log1pf(__expf(-fabsf(l)));
  __syncthreads();
  for (int off = 32; off > 0; off >>= 1) {
    if (i < off) red[i] += red[i + off];
    __syncthreads();
  }
  if (i == 0) dout[0] = red[0] * (1.f / 64.f);
}

// ---------------- launcher ----------------
extern "C" void kernel_launch(void* const* d_in, const int* in_sizes, int n_in,
                              void* d_out, int out_size, void* d_ws, size_t ws_size,
                              hipStream_t stream) {
  const int*   input_ids  = (const int*)d_in[0];
  const int*   seq_label  = (const int*)d_in[3];
  const int*   entity_ids = (const int*)d_in[4];
  const float* embed      = (const float*)d_in[5];
  const float* w_ih0      = (const float*)d_in[6];
  const float* w_hh0      = (const float*)d_in[7];
  const float* b_ih0      = (const float*)d_in[8];
  const float* b_hh0      = (const float*)d_in[9];
  const float* w_ih1      = (const float*)d_in[10];
  const float* w_hh1      = (const float*)d_in[11];
  const float* b_ih1      = (const float*)d_in[12];
  const float* b_hh1      = (const float*)d_in[13];
  const float* pool_w     = (const float*)d_in[14];
  const float* pool_b     = (const float*)d_in[15];
  const float* lin_w      = (const float*)d_in[16];
  const float* lin_b      = (const float*)d_in[17];
  float* out = (float*)d_out;

  const size_t SZ_XO = (size_t)Bb * Ss * Hh * 2;   // 12.58 MB
  const size_t SZ_SY = (size_t)2 * Ss * CPT * 4;   // 512 KB counters
  char* ws = (char*)d_ws;
  size_t off = 0;
  unsigned short* x_bf   = (unsigned short*)(ws + off); off += SZ_XO;
  unsigned short* hseq1  = (unsigned short*)(ws + off); off += SZ_XO;
  unsigned short* hseq2  = (unsigned short*)(ws + off); off += SZ_XO;
  float*          seq_out= (float*)(ws + off);          off += (size_t)Bb * Hh * 4;
  float*          logits = (float*)(ws + off);          off += 1024;
  unsigned int*   syncb  = (unsigned int*)(ws + off);   off += SZ_SY;
  // partial (Ss*NCH x Bb*256 fp32 = 25.17 MB) aliases x_bf+hseq1 (25.17 MB):
  // both dead once k_lstm2 completes; pool kernels run strictly after it.
  float*          partial = (float*)ws;

  hipMemsetAsync(syncb, 0, SZ_SY, stream);

  k_embed<<<Bb * Ss, 256, 0, stream>>>(input_ids, embed, x_bf);

  k_lstm2<<<2 * NWGL, 256, 0, stream>>>(x_bf, w_ih0, w_hh0, w_ih1, w_hh1,
                                        b_ih0, b_hh0, b_ih1, b_hh1,
                                        hseq1, hseq2, syncb);

  dim3 pgrid(Ss, NCH);
  k_pool_partial<<<pgrid, 256, 0, stream>>>(hseq2, pool_w, partial);
  k_pool_reduce<<<(Bb * Hh) / 256, 256, 0, stream>>>(partial, pool_b, seq_out);
  k_entity_logits<<<Bb, 256, 0, stream>>>(hseq2, seq_out, entity_ids, lin_w, lin_b,
                                          logits, out + 1);
  k_loss<<<1, 64, 0, stream>>>(logits, seq_label, out);
}